// Round 1
// baseline (18.876 us; speedup 1.0000x reference)
//
#include <hip/hip_runtime.h>

// Reference reduces exactly to mean(where(up < 0.2, up, 0)):
// the scatter-min writes strictly-positive values (110-i)/50, i<110, into a
// ZERO-initialized buffer -> min(0, pos) = 0 -> right2up == 0 identically,
// pixel_diff = |0 - up| = |up|, masked mean over all B*C*H*W elements.
// So only d_in[0] (up) is ever read. left/right are dead.

#define RED_BLOCKS 2048
#define RED_THREADS 256

__global__ __launch_bounds__(RED_THREADS)
void closs_partial_kernel(const float* __restrict__ up, float* __restrict__ ws, int n4) {
    const float4* __restrict__ up4 = reinterpret_cast<const float4*>(up);
    float acc = 0.0f;
    const int stride = gridDim.x * blockDim.x;
    for (int idx = blockIdx.x * blockDim.x + threadIdx.x; idx < n4; idx += stride) {
        float4 v = up4[idx];
        float ax = fabsf(v.x), ay = fabsf(v.y), az = fabsf(v.z), aw = fabsf(v.w);
        acc += (ax < 0.2f) ? ax : 0.0f;
        acc += (ay < 0.2f) ? ay : 0.0f;
        acc += (az < 0.2f) ? az : 0.0f;
        acc += (aw < 0.2f) ? aw : 0.0f;
    }
    // wave-64 butterfly reduce
    #pragma unroll
    for (int off = 32; off > 0; off >>= 1) acc += __shfl_down(acc, off, 64);
    __shared__ float sdata[RED_THREADS / 64];
    const int lane = threadIdx.x & 63;
    const int wid  = threadIdx.x >> 6;
    if (lane == 0) sdata[wid] = acc;
    __syncthreads();
    if (threadIdx.x == 0) {
        float s = 0.0f;
        #pragma unroll
        for (int w = 0; w < RED_THREADS / 64; ++w) s += sdata[w];
        ws[blockIdx.x] = s;
    }
}

__global__ __launch_bounds__(RED_THREADS)
void closs_final_kernel(const float* __restrict__ ws, float* __restrict__ out,
                        int nblocks, float inv_n) {
    float acc = 0.0f;
    for (int idx = threadIdx.x; idx < nblocks; idx += blockDim.x) acc += ws[idx];
    #pragma unroll
    for (int off = 32; off > 0; off >>= 1) acc += __shfl_down(acc, off, 64);
    __shared__ float sdata[RED_THREADS / 64];
    const int lane = threadIdx.x & 63;
    const int wid  = threadIdx.x >> 6;
    if (lane == 0) sdata[wid] = acc;
    __syncthreads();
    if (threadIdx.x == 0) {
        float s = 0.0f;
        #pragma unroll
        for (int w = 0; w < RED_THREADS / 64; ++w) s += sdata[w];
        out[0] = s * inv_n;
    }
}

extern "C" void kernel_launch(void* const* d_in, const int* in_sizes, int n_in,
                              void* d_out, int out_size, void* d_ws, size_t ws_size,
                              hipStream_t stream) {
    const float* up = (const float*)d_in[0];
    float* out = (float*)d_out;
    float* ws  = (float*)d_ws;   // needs RED_BLOCKS * 4 bytes = 8 KiB

    const int n  = in_sizes[0];          // 64*1*512*512 = 16,777,216 (divisible by 4)
    const int n4 = n >> 2;
    const float inv_n = 1.0f / (float)n;

    closs_partial_kernel<<<RED_BLOCKS, RED_THREADS, 0, stream>>>(up, ws, n4);
    closs_final_kernel<<<1, RED_THREADS, 0, stream>>>(ws, out, RED_BLOCKS, inv_n);
}